// Round 3
// baseline (436.249 us; speedup 1.0000x reference)
//
#include <hip/hip_runtime.h>
#include <hip/hip_fp16.h>
#include <cstdint>

// ---------- types ----------
typedef _Float16 half8 __attribute__((ext_vector_type(8)));
typedef _Float16 half4 __attribute__((ext_vector_type(4)));
typedef float floatx4 __attribute__((ext_vector_type(4)));

#define S_TOT 8192
#define H_DIM 1152
#define NHEAD 16
#define HD 72
#define QSTR 96      // Q row stride (els), zeros in 72..95
#define KSTR 104     // K row stride (els), zeros in 72..95, 96..103 never read
#define NSEG 8
#define SEGL 1024
// 72^-0.5 * log2(e): exp2-based softmax, scale folded into Q
#define QSCALE 0.17002324631230988f
#define VT_TILE 5760   // 80*72 els per (n,h,kb) V^T tile

// async global->LDS 16B (wave-uniform LDS base + lane*16)
__device__ __forceinline__ void gld_lds16(const void* g, void* l) {
  __builtin_amdgcn_global_load_lds((const __attribute__((address_space(1))) void*)g,
                                   (__attribute__((address_space(3))) void*)l, 16, 0, 0);
}

// ---------- elementwise cast fp32 -> f16 ----------
__global__ void cast_f32_f16(const float* __restrict__ in, _Float16* __restrict__ out, int n) {
  int i = (blockIdx.x * 256 + threadIdx.x) * 4;
  if (i < n) {
    float4 v = *(const float4*)(in + i);
    half4 o = { (_Float16)v.x, (_Float16)v.y, (_Float16)v.z, (_Float16)v.w };
    *(half4*)(out + i) = o;
  }
}

// ---------- transpose + cast: W[R][C] fp32 -> Wt[C][R] f16 ----------
__global__ void transpose_cast(const float* __restrict__ W, _Float16* __restrict__ Wt,
                               int R, int C) {
  __shared__ float tile[32][33];
  int tx = threadIdx.x, ty = threadIdx.y;          // (32,8)
  int bx = blockIdx.x, by = blockIdx.y;
#pragma unroll
  for (int i = 0; i < 4; ++i)
    tile[ty + i * 8][tx] = W[(size_t)(by * 32 + ty + i * 8) * C + bx * 32 + tx];
  __syncthreads();
#pragma unroll
  for (int i = 0; i < 4; ++i)
    Wt[(size_t)(bx * 32 + ty + i * 8) * R + by * 32 + tx] = (_Float16)tile[tx][ty + i * 8];
}

// ---------- GEMM: C[M][N] = A[M][K] @ Bt[N][K]^T + bias  (m97-style, f16 MFMA) ----------
template <bool OUT_HALF>
__global__ __launch_bounds__(256) void gemm_bt(
    const _Float16* __restrict__ A, const _Float16* __restrict__ Bt,
    const float* __restrict__ bias, float* __restrict__ Cf, _Float16* __restrict__ Ch,
    int M, int N, int K) {
  __shared__ __align__(16) _Float16 As[128 * 32];
  __shared__ __align__(16) _Float16 Bs[128 * 32];
  const int tid = threadIdx.x;
  const int lane = tid & 63, w = tid >> 6;
  const int quad = lane >> 4, l16 = lane & 15;
  const int wm = w >> 1, wn = w & 1;
  const int m0 = blockIdx.y * 128, n0 = blockIdx.x * 128;

  floatx4 acc[4][4] = {};

  for (int kt = 0; kt < K; kt += 32) {
    __syncthreads();
#pragma unroll
    for (int i = 0; i < 2; ++i) {
      int off = tid * 16 + i * 4096;
      int row = off >> 6, colb = off & 63;
      gld_lds16((const char*)(A + (size_t)(m0 + row) * K + kt) + colb, (char*)As + off);
      gld_lds16((const char*)(Bt + (size_t)(n0 + row) * K + kt) + colb, (char*)Bs + off);
    }
    __syncthreads();
    half8 af[4], bf[4];
#pragma unroll
    for (int im = 0; im < 4; ++im)
      af[im] = *(const half8*)&As[(wm * 64 + im * 16 + l16) * 32 + quad * 8];
#pragma unroll
    for (int in = 0; in < 4; ++in)
      bf[in] = *(const half8*)&Bs[(wn * 64 + in * 16 + l16) * 32 + quad * 8];
#pragma unroll
    for (int im = 0; im < 4; ++im)
#pragma unroll
      for (int in = 0; in < 4; ++in)
        acc[im][in] = __builtin_amdgcn_mfma_f32_16x16x32_f16(af[im], bf[in], acc[im][in], 0, 0, 0);
  }
#pragma unroll
  for (int im = 0; im < 4; ++im) {
    int m = m0 + wm * 64 + im * 16 + quad * 4;
#pragma unroll
    for (int in = 0; in < 4; ++in) {
      int n = n0 + wn * 64 + in * 16 + l16;
      float b = bias[n];
#pragma unroll
      for (int r = 0; r < 4; ++r) {
        float v = acc[im][in][r] + b;
        if (OUT_HALF) Ch[(size_t)(m + r) * N + n] = (_Float16)v;
        else          Cf[(size_t)(m + r) * N + n] = v;
      }
    }
  }
}

// ---------- RoPE Q,K -> padded [seg*NH][L][{96,104}] f16, Q pre-scaled ----------
__global__ void rope_scatter(const _Float16* __restrict__ QKV,  // [S][3456]
                             const float* __restrict__ cosb,    // [S][72]
                             const float* __restrict__ sinb,
                             _Float16* __restrict__ Qo, _Float16* __restrict__ Ko) {
  int t = blockIdx.x * 256 + threadIdx.x;  // (s,h)
  int s = t >> 4, h = t & 15;
  int n = s >> 10, l = s & 1023;
  const _Float16* q = QKV + (size_t)s * 3456 + h * HD;
  const _Float16* k = q + H_DIM;
  const float* cs = cosb + (size_t)s * HD;
  const float* sn = sinb + (size_t)s * HD;
  size_t row = ((size_t)(n * NHEAD + h)) * SEGL + l;
  size_t qo = row * QSTR, ko = row * KSTR;
  half8 z = {};
  {
    _Float16 qr[72], qv[72];
#pragma unroll
    for (int i = 0; i < 9; ++i) *(half8*)&qr[8 * i] = *(const half8*)(q + 8 * i);
#pragma unroll
    for (int d = 0; d < 36; ++d) {
      float c0 = cs[d], s0 = sn[d], c1 = cs[d + 36], s1 = sn[d + 36];
      float a = (float)qr[d], b = (float)qr[d + 36];
      qv[d]      = (_Float16)((a * c0 - b * s0) * QSCALE);
      qv[d + 36] = (_Float16)((b * c1 + a * s1) * QSCALE);
    }
#pragma unroll
    for (int i = 0; i < 9; ++i) *(half8*)(Qo + qo + 8 * i) = *(half8*)&qv[8 * i];
#pragma unroll
    for (int i = 9; i < 12; ++i) *(half8*)(Qo + qo + 8 * i) = z;
  }
  {
    _Float16 kr[72], kv[72];
#pragma unroll
    for (int i = 0; i < 9; ++i) *(half8*)&kr[8 * i] = *(const half8*)(k + 8 * i);
#pragma unroll
    for (int d = 0; d < 36; ++d) {
      float c0 = cs[d], s0 = sn[d], c1 = cs[d + 36], s1 = sn[d + 36];
      float a = (float)kr[d], b = (float)kr[d + 36];
      kv[d]      = (_Float16)(a * c0 - b * s0);
      kv[d + 36] = (_Float16)(b * c1 + a * s1);
    }
#pragma unroll
    for (int i = 0; i < 9; ++i) *(half8*)(Ko + ko + 8 * i) = *(half8*)&kv[8 * i];
#pragma unroll
    for (int i = 9; i < 12; ++i) *(half8*)(Ko + ko + 8 * i) = z;
    // els 96..103 left unwritten: staged to LDS but never read by MFMA
  }
}

// ---------- V pre-transpose: QKVb V-cols -> Vt tiles [n,h,kb][d:80][72] ----------
__global__ __launch_bounds__(256) void transpose_v(const _Float16* __restrict__ QKV,
                                                   _Float16* __restrict__ Vt) {
  __shared__ __align__(16) _Float16 Vs[64 * 88];   // [key][d pad 88]
  const int tid = threadIdx.x;
  const int kb = blockIdx.x, h = blockIdx.y, n = blockIdx.z;
  const int s0 = n * SEGL + kb * 64;
  const _Float16* src = QKV + (size_t)s0 * 3456 + 2 * H_DIM + h * HD;
  // load 64 keys x 72 d (9 half8 per key)
  for (int idx = tid; idx < 576; idx += 256) {
    int key = idx / 9, c = idx - key * 9;
    *(half8*)&Vs[key * 88 + c * 8] = *(const half8*)(src + (size_t)key * 3456 + c * 8);
  }
  __syncthreads();
  _Float16* dst = Vt + (((size_t)(n * NHEAD + h)) * 16 + kb) * VT_TILE;
  for (int idx = tid; idx < 720; idx += 256) {  // 80 rows x 9 chunks
    int d = idx / 9, c = idx - d * 9;
    half8 v;
    if (d < HD) {
#pragma unroll
      for (int j = 0; j < 8; ++j) v[j] = Vs[(c * 8 + j) * 88 + d];
    } else {
      v = half8{};
    }
    *(half8*)(dst + d * 72 + c * 8) = v;
  }
}

// ---------- flash attention (S^T scheme): block = (qb,h,n), 128 q, 4 waves x 32 q ----------
__global__ __launch_bounds__(256) void attn_kernel(
    const _Float16* __restrict__ Qb, const _Float16* __restrict__ Kb,
    const _Float16* __restrict__ Vtb, _Float16* __restrict__ Ctx) {
  __shared__ __align__(16) _Float16 Kt[64 * KSTR];   // [key][104]  13312 B
  __shared__ __align__(16) _Float16 Vt[80 * 72];     // [d][key72]  11520 B
  __shared__ __align__(16) _Float16 Ps[4 * 32 * 72]; // [wave][q32][key72] 18432 B
  const int tid = threadIdx.x;
  const int lane = tid & 63, w = tid >> 6;
  const int quad = lane >> 4, l16 = lane & 15;
  const int qb = blockIdx.x, h = blockIdx.y, n = blockIdx.z;
  const size_t hseg = (size_t)(n * NHEAD + h);
  const _Float16* Qg = Qb + hseg * SEGL * QSTR;
  const _Float16* Kg = Kb + hseg * SEGL * KSTR;
  const _Float16* Vg = Vtb + hseg * 16 * VT_TILE;

  // Q as B-operand fragments: lane holds Q[q=l16][k=quad*8+j]
  half8 qf[2][3];
#pragma unroll
  for (int qg = 0; qg < 2; ++qg) {
    int row = qb * 128 + w * 32 + qg * 16 + l16;
#pragma unroll
    for (int kc = 0; kc < 3; ++kc)
      qf[qg][kc] = *(const half8*)(Qg + (size_t)row * QSTR + kc * 32 + quad * 8);
  }
  float m_s[2] = {-1e30f, -1e30f}, l_s[2] = {0.f, 0.f};
  floatx4 o_acc[2][5] = {};   // O^T[d = t*16+quad*4+r][q = l16], t<5 (d<80)

  for (int kb = 0; kb < SEGL / 64; ++kb) {
    __syncthreads();
    // K tile: contiguous 64*104*2 = 13312 B
    {
      const char* base = (const char*)(Kg + (size_t)kb * 64 * KSTR);
#pragma unroll
      for (int i = 0; i < 3; ++i)
        gld_lds16(base + tid * 16 + i * 4096, (char*)Kt + tid * 16 + i * 4096);
      if (tid < 64)
        gld_lds16(base + 12288 + tid * 16, (char*)Kt + 12288 + tid * 16);
    }
    // V^T tile: contiguous 80*72*2 = 11520 B
    {
      const char* base = (const char*)(Vg + (size_t)kb * VT_TILE);
#pragma unroll
      for (int i = 0; i < 2; ++i)
        gld_lds16(base + tid * 16 + i * 4096, (char*)Vt + tid * 16 + i * 4096);
      if (tid < 208)
        gld_lds16(base + 8192 + tid * 16, (char*)Vt + 8192 + tid * 16);
    }
    __syncthreads();
    // S^T = K·Q^T
    floatx4 sa[2][4] = {};
#pragma unroll
    for (int nt = 0; nt < 4; ++nt) {
#pragma unroll
      for (int kc = 0; kc < 3; ++kc) {
        half8 kf = *(const half8*)&Kt[(nt * 16 + l16) * KSTR + kc * 32 + quad * 8];
        sa[0][nt] = __builtin_amdgcn_mfma_f32_16x16x32_f16(kf, qf[0][kc], sa[0][nt], 0, 0, 0);
        sa[1][nt] = __builtin_amdgcn_mfma_f32_16x16x32_f16(kf, qf[1][kc], sa[1][nt], 0, 0, 0);
      }
    }
    // online softmax: per-lane column q=l16; in-lane then cross-quad reduce
#pragma unroll
    for (int qg = 0; qg < 2; ++qg) {
      float mx = -1e30f;
#pragma unroll
      for (int nt = 0; nt < 4; ++nt)
#pragma unroll
        for (int r = 0; r < 4; ++r) mx = fmaxf(mx, sa[qg][nt][r]);
      mx = fmaxf(mx, __shfl_xor(mx, 16, 64));
      mx = fmaxf(mx, __shfl_xor(mx, 32, 64));
      float mnew = fmaxf(m_s[qg], mx);
      float alpha = exp2f(m_s[qg] - mnew);
      float sum = 0.f;
#pragma unroll
      for (int nt = 0; nt < 4; ++nt)
#pragma unroll
        for (int r = 0; r < 4; ++r) {
          float p = exp2f(sa[qg][nt][r] - mnew);
          sa[qg][nt][r] = p;
          sum += p;
        }
      sum += __shfl_xor(sum, 16, 64);
      sum += __shfl_xor(sum, 32, 64);
      l_s[qg] = l_s[qg] * alpha + sum;
      m_s[qg] = mnew;
#pragma unroll
      for (int t = 0; t < 5; ++t) o_acc[qg][t] *= alpha;
      int prow = (w * 32 + qg * 16 + l16) * 72;
#pragma unroll
      for (int nt = 0; nt < 4; ++nt) {
        half4 ph = { (_Float16)sa[qg][nt][0], (_Float16)sa[qg][nt][1],
                     (_Float16)sa[qg][nt][2], (_Float16)sa[qg][nt][3] };
        *(half4*)&Ps[prow + nt * 16 + quad * 4] = ph;
      }
    }
    // O^T += V^T·P^T   (wave-private P, no barrier needed)
#pragma unroll
    for (int kc2 = 0; kc2 < 2; ++kc2) {
      half8 pb0 = *(const half8*)&Ps[(w * 32 + l16) * 72 + kc2 * 32 + quad * 8];
      half8 pb1 = *(const half8*)&Ps[(w * 32 + 16 + l16) * 72 + kc2 * 32 + quad * 8];
#pragma unroll
      for (int t = 0; t < 5; ++t) {
        half8 vf = *(const half8*)&Vt[(t * 16 + l16) * 72 + kc2 * 32 + quad * 8];
        o_acc[0][t] = __builtin_amdgcn_mfma_f32_16x16x32_f16(vf, pb0, o_acc[0][t], 0, 0, 0);
        o_acc[1][t] = __builtin_amdgcn_mfma_f32_16x16x32_f16(vf, pb1, o_acc[1][t], 0, 0, 0);
      }
    }
  }
  // epilogue: lane holds d = t*16+quad*4+r for q=l16 -> half4 stores
#pragma unroll
  for (int qg = 0; qg < 2; ++qg) {
    float rl = 1.0f / l_s[qg];
    size_t s2 = (size_t)n * SEGL + qb * 128 + w * 32 + qg * 16 + l16;
#pragma unroll
    for (int t = 0; t < 5; ++t) {
      int d0 = t * 16 + quad * 4;
      if (d0 < HD) {
        half4 hv = { (_Float16)(o_acc[qg][t][0] * rl), (_Float16)(o_acc[qg][t][1] * rl),
                     (_Float16)(o_acc[qg][t][2] * rl), (_Float16)(o_acc[qg][t][3] * rl) };
        *(half4*)&Ctx[s2 * H_DIM + h * HD + d0] = hv;
      }
    }
  }
}

extern "C" void kernel_launch(void* const* d_in, const int* in_sizes, int n_in,
                              void* d_out, int out_size, void* d_ws, size_t ws_size,
                              hipStream_t stream) {
  const float* X    = (const float*)d_in[0];
  const float* cosb = (const float*)d_in[1];
  const float* sinb = (const float*)d_in[2];
  const float* Wqkv = (const float*)d_in[3];
  const float* bqkv = (const float*)d_in[4];
  const float* Wout = (const float*)d_in[5];
  const float* bout = (const float*)d_in[6];
  float* out = (float*)d_out;
  char* ws = (char*)d_ws;

  _Float16* Xb   = (_Float16*)(ws);              // 18,874,368 (reused as Ctx)
  _Float16* Wqt  = (_Float16*)(ws + 18874368);   //  7,962,624
  _Float16* Wot  = (_Float16*)(ws + 26836992);   //  2,654,208
  _Float16* QKVb = (_Float16*)(ws + 29491200);   // 56,623,104
  _Float16* Qb   = (_Float16*)(ws + 86114304);   // 128*1024*96*2  = 25,165,824
  _Float16* Kb   = (_Float16*)(ws + 111280128);  // 128*1024*104*2 = 27,262,976
  _Float16* Vtb  = (_Float16*)(ws + 138543104);  // 128*16*5760*2  = 23,592,960
  _Float16* Ctx  = Xb;                           // gemm1 consumed Xb before attn writes

  cast_f32_f16<<<9216, 256, 0, stream>>>(X, Xb, S_TOT * H_DIM);
  transpose_cast<<<dim3(108, 36), dim3(32, 8), 0, stream>>>(Wqkv, Wqt, H_DIM, 3 * H_DIM);
  transpose_cast<<<dim3(36, 36), dim3(32, 8), 0, stream>>>(Wout, Wot, H_DIM, H_DIM);
  gemm_bt<true><<<dim3(27, 64), 256, 0, stream>>>(Xb, Wqt, bqkv, nullptr, QKVb,
                                                  S_TOT, 3 * H_DIM, H_DIM);
  rope_scatter<<<512, 256, 0, stream>>>(QKVb, cosb, sinb, Qb, Kb);
  transpose_v<<<dim3(16, 16, 8), 256, 0, stream>>>(QKVb, Vtb);
  attn_kernel<<<dim3(8, 16, 8), 256, 0, stream>>>(Qb, Kb, Vtb, Ctx);
  gemm_bt<false><<<dim3(9, 64), 256, 0, stream>>>(Ctx, Wot, bout, out, nullptr,
                                                  S_TOT, H_DIM, H_DIM);
}